// Round 6
// baseline (166.345 us; speedup 1.0000x reference)
//
#include <hip/hip_runtime.h>

#define BN_EPS 1e-5f

typedef _Float16 half8 __attribute__((ext_vector_type(8)));
typedef float f32x4 __attribute__((ext_vector_type(4)));

__device__ __forceinline__ float tanh_fast(float x){
  float e = __expf(2.0f * x);
  return 1.0f - 2.0f / (e + 1.0f);
}

// ---------------- prep: W1 -> fp16 in MFMA-fragment order + BN scale/shift ----------------
// Fragment (q,c): q = k-chunk (32 k each, 0..7), c = col-block (16 e each, 0..15).
// lane l = kg*16+lr holds 8 halves: e = c*16+lr, d = q*32+kg*8+j.
__global__ __launch_bounds__(256) void k_prep(const float* __restrict__ W1,
    const float* __restrict__ gamma, const float* __restrict__ beta,
    const float* __restrict__ rmean, const float* __restrict__ rvar,
    _Float16* __restrict__ Bp2, float* __restrict__ bns, float* __restrict__ bnb){
  int i = blockIdx.x * 256 + threadIdx.x;   // 0..65535
  int j  = i & 7;
  int l  = (i >> 3) & 63;
  int c  = (i >> 9) & 15;
  int q  = (i >> 13) & 7;
  int lr = l & 15, kg = l >> 4;
  int e  = c * 16 + lr;
  int d  = q * 32 + kg * 8 + j;
  Bp2[i] = (_Float16)W1[e * 256 + d];
  if (i < 4096){
    float sc = gamma[i] * rsqrtf(rvar[i] + BN_EPS);
    bns[i] = sc;
    bnb[i] = beta[i] - rmean[i] * sc;
  }
}

// ---------------- fused GEMM + BN + tanh + dot(x_h) + local softmax + weighted tile sum ----------------
// 256 thr (4 waves), BM=64 x BN=256, K=256 as 2 compute steps of BK=128.
// Depth-2 column-chunk pipeline: chunks c2,c3 stay IN FLIGHT across barrier 1
// (raw s_barrier + lgkmcnt-only wait -> no vmcnt drain), consumed after step-A's
// 64 MFMAs. A tile: full 64x256 fp16 LDS, XOR swizzle, survives for epilogue.
__global__ __launch_bounds__(256, 4) void k_fused(const float* __restrict__ xh,
    const float* __restrict__ xhpre, const _Float16* __restrict__ Bp,
    const float* __restrict__ bns, const float* __restrict__ bnb,
    float* __restrict__ Pbuf, float2* __restrict__ mz){
  constexpr int S = 4096, Dd = 256;
  const int bid = blockIdx.x;       // 64 b * 64 chunks
  const int b  = bid >> 6;
  const int s0 = (bid & 63) * 64;
  const int tid = threadIdx.x;
  const int lane = tid & 63;
  const int w = tid >> 6;        // 0..3 = col-block owner
  const int kg = lane >> 4;      // 0..3
  const int lr = lane & 15;      // 0..15

  __shared__ _Float16 A[64 * 256];           // 32 KB, XOR-swizzled rows
  __shared__ float bnsc[64], bnsh[64];
  __shared__ float red[4][64];
  __shared__ f32x4 red4[4][64];
  __shared__ float wrow[64];
  char* Ab = (char*)A;

  if (tid < 64){ bnsc[tid] = bns[s0 + tid]; bnsh[tid] = bnb[s0 + tid]; }

  float xhv[4];
  #pragma unroll
  for (int nt = 0; nt < 4; ++nt) xhv[nt] = xh[b * 256 + w * 64 + nt * 16 + lr];

  const float* Abase = xhpre + ((size_t)b * S + s0) * Dd;

  // per-thread staging rows: w*16 + i*4 + kg, floats [c*64 + lr*4, +4)
#define ISSUE(buf, c) \
  _Pragma("unroll") \
  for (int i = 0; i < 4; ++i){ \
    int row = w * 16 + i * 4 + kg; \
    buf[i] = *reinterpret_cast<const float4*>(Abase + (size_t)row * Dd + (c) * 64 + lr * 4); \
  }
#define CVTW(buf, c) \
  _Pragma("unroll") \
  for (int i = 0; i < 4; ++i){ \
    int row = w * 16 + i * 4 + kg; \
    union { _Float16 h[4]; uint2 u; } pk; \
    pk.h[0]=(_Float16)buf[i].x; pk.h[1]=(_Float16)buf[i].y; \
    pk.h[2]=(_Float16)buf[i].z; pk.h[3]=(_Float16)buf[i].w; \
    int byte = (row * 512 + (c) * 128 + lr * 8) ^ ((row & 7) << 4); \
    *reinterpret_cast<uint2*>(Ab + byte) = pk.u; \
  }

  float4 bufA[4], bufB[4], bufC[4], bufD[4];
  ISSUE(bufA, 0); ISSUE(bufB, 1);
  CVTW(bufA, 0);  ISSUE(bufC, 2);
  CVTW(bufB, 1);  ISSUE(bufD, 3);
  // barrier 1: order LDS writes only; chunks c2,c3 remain in flight (no vmcnt drain)
  asm volatile("s_waitcnt lgkmcnt(0)" ::: "memory");
  __builtin_amdgcn_s_barrier();

  f32x4 acc[4][4] = {};

  // ---- step A: q = 0..3 (cols 0..127) ----
  #pragma unroll
  for (int q = 0; q < 4; ++q){
    half8 afr[4], bfr[4];
    #pragma unroll
    for (int nt = 0; nt < 4; ++nt)
      bfr[nt] = *reinterpret_cast<const half8*>(Bp + ((size_t)((q * 16 + w * 4 + nt) * 64 + lane)) * 8);
    #pragma unroll
    for (int mt = 0; mt < 4; ++mt){
      int row = mt * 16 + lr;
      int byte = (row * 512 + q * 64 + kg * 16) ^ ((row & 7) << 4);
      afr[mt] = *reinterpret_cast<const half8*>(Ab + byte);
    }
    #pragma unroll
    for (int mt = 0; mt < 4; ++mt)
      #pragma unroll
      for (int nt = 0; nt < 4; ++nt)
        acc[mt][nt] = __builtin_amdgcn_mfma_f32_16x16x32_f16(afr[mt], bfr[nt], acc[mt][nt], 0, 0, 0);
  }

  // write step-B data (waits on c2/c3 arrival; disjoint LDS columns -> no race with step-A reads)
  CVTW(bufC, 2); CVTW(bufD, 3);
  __syncthreads();

  // ---- step B: q = 4..7 (cols 128..255) ----
  #pragma unroll
  for (int q = 4; q < 8; ++q){
    half8 afr[4], bfr[4];
    #pragma unroll
    for (int nt = 0; nt < 4; ++nt)
      bfr[nt] = *reinterpret_cast<const half8*>(Bp + ((size_t)((q * 16 + w * 4 + nt) * 64 + lane)) * 8);
    #pragma unroll
    for (int mt = 0; mt < 4; ++mt){
      int row = mt * 16 + lr;
      int byte = (row * 512 + q * 64 + kg * 16) ^ ((row & 7) << 4);
      afr[mt] = *reinterpret_cast<const half8*>(Ab + byte);
    }
    #pragma unroll
    for (int mt = 0; mt < 4; ++mt)
      #pragma unroll
      for (int nt = 0; nt < 4; ++nt)
        acc[mt][nt] = __builtin_amdgcn_mfma_f32_16x16x32_f16(afr[mt], bfr[nt], acc[mt][nt], 0, 0, 0);
  }
#undef ISSUE
#undef CVTW

  // ---- a_t epilogue: BN + tanh + dot(x_h); reduce 16 cols (lr) per wave ----
  #pragma unroll
  for (int mt = 0; mt < 4; ++mt){
    #pragma unroll
    for (int r = 0; r < 4; ++r){
      int row = mt * 16 + kg * 4 + r;   // C/D: col=lane&15, row=(lane>>4)*4+reg
      float sc = bnsc[row], sh = bnsh[row];
      float sum = 0.f;
      #pragma unroll
      for (int nt = 0; nt < 4; ++nt){
        float hv = fmaf(acc[mt][nt][r], sc, sh);
        sum = fmaf(tanh_fast(hv), xhv[nt], sum);
      }
      sum += __shfl_xor(sum, 1);
      sum += __shfl_xor(sum, 2);
      sum += __shfl_xor(sum, 4);
      sum += __shfl_xor(sum, 8);
      if (lr == 0) red[w][row] = sum;
    }
  }
  __syncthreads();

  // ---- local softmax stats over 64 rows (wave 0) ----
  if (w == 0){
    float v = red[0][lane] + red[1][lane] + red[2][lane] + red[3][lane];
    float m_c = v;
    #pragma unroll
    for (int o = 1; o < 64; o <<= 1) m_c = fmaxf(m_c, __shfl_xor(m_c, o));
    float wv = __expf(v - m_c);
    wrow[lane] = wv;
    float z_c = wv;
    #pragma unroll
    for (int o = 1; o < 64; o <<= 1) z_c += __shfl_xor(z_c, o);
    if (lane == 0) mz[bid] = make_float2(m_c, z_c);
  }
  __syncthreads();

  // ---- weighted tile sum: P_c[d] = sum_rows wrow[row]*x[row][d], from LDS fp16 ----
  f32x4 pacc = {0.f, 0.f, 0.f, 0.f};
  #pragma unroll
  for (int r = 0; r < 16; ++r){
    int row = w * 16 + r;
    float wgt = wrow[row];
    int byte = (row * 512 + lane * 8) ^ ((row & 7) << 4);
    union { _Float16 h[4]; uint2 u; } pk;
    pk.u = *reinterpret_cast<const uint2*>(Ab + byte);
    pacc[0] = fmaf(wgt, (float)pk.h[0], pacc[0]);
    pacc[1] = fmaf(wgt, (float)pk.h[1], pacc[1]);
    pacc[2] = fmaf(wgt, (float)pk.h[2], pacc[2]);
    pacc[3] = fmaf(wgt, (float)pk.h[3], pacc[3]);
  }
  red4[w][lane] = pacc;
  __syncthreads();
  if (tid < 64){
    f32x4 r = red4[0][tid] + red4[1][tid] + red4[2][tid] + red4[3][tid];
    *reinterpret_cast<f32x4*>(Pbuf + (size_t)bid * 256 + tid * 4) = r;
  }
}

// ---------------- combine 64 chunks per b: flash-style merge + W2 scale ----------------
__global__ __launch_bounds__(256) void k_combine(const float* __restrict__ Pbuf,
    const float2* __restrict__ mz, const float* __restrict__ W2, float* __restrict__ out){
  int b = blockIdx.x, d = threadIdx.x;
  __shared__ float2 smz[64];
  if (d < 64) smz[d] = mz[b * 64 + d];
  __syncthreads();
  float M = smz[0].x;
  #pragma unroll
  for (int c = 1; c < 64; ++c) M = fmaxf(M, smz[c].x);
  float Z = 0.f, acc = 0.f;
  #pragma unroll 8
  for (int c = 0; c < 64; ++c){
    float e = __expf(smz[c].x - M);
    Z += smz[c].y * e;
    acc = fmaf(e, Pbuf[(size_t)(b * 64 + c) * 256 + d], acc);
  }
  out[b * 256 + d] = acc * W2[d] / Z;
}

extern "C" void kernel_launch(void* const* d_in, const int* in_sizes, int n_in,
                              void* d_out, int out_size, void* d_ws, size_t ws_size,
                              hipStream_t stream){
  const float* x_h    = (const float*)d_in[0];
  const float* x_hpre = (const float*)d_in[1];
  const float* W1     = (const float*)d_in[2];
  const float* W2     = (const float*)d_in[3];
  const float* gamma  = (const float*)d_in[4];
  const float* beta   = (const float*)d_in[5];
  const float* rmean  = (const float*)d_in[6];
  const float* rvar   = (const float*)d_in[7];
  float* out = (float*)d_out;

  char* ws = (char*)d_ws;
  _Float16* Bp = (_Float16*)(ws);            // 131072 B (fragment-ordered W1)
  float* bns   = (float*)(ws + 131072);      // 16 KB
  float* bnb   = (float*)(ws + 147456);      // 16 KB
  float* Pbuf  = (float*)(ws + 163840);      // 4 MB (64*64 chunks * 256 f32)
  float2* mzb  = (float2*)(ws + 4358144);    // 32 KB  (total ~4.4 MB)

  hipLaunchKernelGGL(k_prep,    dim3(256),  dim3(256), 0, stream, W1, gamma, beta, rmean, rvar, Bp, bns, bnb);
  hipLaunchKernelGGL(k_fused,   dim3(4096), dim3(256), 0, stream, x_h, x_hpre, Bp, bns, bnb, Pbuf, mzb);
  hipLaunchKernelGGL(k_combine, dim3(64),   dim3(256), 0, stream, Pbuf, mzb, W2, out);
}

// Round 7
// 104.348 us; speedup vs baseline: 1.5941x; 1.5941x over previous
//
#include <hip/hip_runtime.h>

#define BN_EPS 1e-5f

typedef _Float16 half8 __attribute__((ext_vector_type(8)));
typedef float f32x4 __attribute__((ext_vector_type(4)));

__device__ __forceinline__ float tanh_fast(float x){
  float e = __expf(2.0f * x);
  return 1.0f - 2.0f / (e + 1.0f);
}

// ---------------- prep: W1 -> fp16 in MFMA-fragment order + BN scale/shift ----------------
// Fragment (q,c): q = k-chunk (32 k each, 0..7), c = col-block (16 e each, 0..15).
// lane l = kg*16+lr holds 8 halves: e = c*16+lr, d = q*32+kg*8+j.
__global__ __launch_bounds__(256) void k_prep(const float* __restrict__ W1,
    const float* __restrict__ gamma, const float* __restrict__ beta,
    const float* __restrict__ rmean, const float* __restrict__ rvar,
    _Float16* __restrict__ Bp2, float* __restrict__ bns, float* __restrict__ bnb){
  int i = blockIdx.x * 256 + threadIdx.x;   // 0..65535
  int j  = i & 7;
  int l  = (i >> 3) & 63;
  int c  = (i >> 9) & 15;
  int q  = (i >> 13) & 7;
  int lr = l & 15, kg = l >> 4;
  int e  = c * 16 + lr;
  int d  = q * 32 + kg * 8 + j;
  Bp2[i] = (_Float16)W1[e * 256 + d];
  if (i < 4096){
    float sc = gamma[i] * rsqrtf(rvar[i] + BN_EPS);
    bns[i] = sc;
    bnb[i] = beta[i] - rmean[i] * sc;
  }
}

// ---------------- fused GEMM + BN + tanh + dot(x_h) + local softmax + weighted tile sum ----------------
// 256 thr (4 waves), BM=32 x BN=256, K=256 as 2 compute steps of BK=128.
// Register-lean depth-2 pipeline: chunks c2,c3 (8 VGPR each) stay in flight across
// barrier 1 (lgkmcnt-only wait + raw s_barrier -> no vmcnt drain), consumed after
// step-A's 32 MFMAs. acc = 32 regs (half of round 6) so the (256,4) cap does NOT
// spill (round-6 lesson: AGPRs count against the unified launch_bounds cap).
// A tile: full 32x256 fp16 LDS (16KB), XOR swizzle, survives for the epilogue.
__global__ __launch_bounds__(256, 4) void k_fused(const float* __restrict__ xh,
    const float* __restrict__ xhpre, const _Float16* __restrict__ Bp,
    const float* __restrict__ bns, const float* __restrict__ bnb,
    float* __restrict__ Pbuf, float2* __restrict__ mz){
  constexpr int S = 4096, Dd = 256;
  const int bid = blockIdx.x;       // 64 b * 128 chunks
  const int b  = bid >> 7;
  const int s0 = (bid & 127) * 32;
  const int tid = threadIdx.x;
  const int lane = tid & 63;
  const int w = tid >> 6;        // 0..3 = col-block owner
  const int kg = lane >> 4;      // 0..3
  const int lr = lane & 15;      // 0..15

  __shared__ _Float16 A[32 * 256];           // 16 KB, XOR-swizzled rows
  __shared__ float bnsc[32], bnsh[32];
  __shared__ float red[4][32];
  __shared__ f32x4 red4[4][64];              // 4 KB
  __shared__ float wrow[32];
  char* Ab = (char*)A;

  if (tid < 32){ bnsc[tid] = bns[s0 + tid]; bnsh[tid] = bnb[s0 + tid]; }

  float xhv[4];
  #pragma unroll
  for (int nt = 0; nt < 4; ++nt) xhv[nt] = xh[b * 256 + w * 64 + nt * 16 + lr];

  const float* Abase = xhpre + ((size_t)b * S + s0) * Dd;
  const int srow = tid >> 4;        // 0..15 (+16 for i=1)
  const int sc4  = tid & 15;        // float4 slot within 64-float chunk

  // per-thread staging: 2 rows (srow, srow+16), 16B each, per 64-col chunk
#define ISSUE(buf, c) \
  _Pragma("unroll") \
  for (int i = 0; i < 2; ++i){ \
    int row = srow + i * 16; \
    buf[i] = *reinterpret_cast<const float4*>(Abase + (size_t)row * Dd + (c) * 64 + sc4 * 4); \
  }
#define CVTW(buf, c) \
  _Pragma("unroll") \
  for (int i = 0; i < 2; ++i){ \
    int row = srow + i * 16; \
    union { _Float16 h[4]; uint2 u; } pk; \
    pk.h[0]=(_Float16)buf[i].x; pk.h[1]=(_Float16)buf[i].y; \
    pk.h[2]=(_Float16)buf[i].z; pk.h[3]=(_Float16)buf[i].w; \
    int byte = (row * 512 + (c) * 128 + sc4 * 8) ^ ((row & 7) << 4); \
    *reinterpret_cast<uint2*>(Ab + byte) = pk.u; \
  }

  float4 bufA[2], bufB[2], bufC[2], bufD[2];
  ISSUE(bufA, 0); ISSUE(bufB, 1);
  CVTW(bufA, 0);  ISSUE(bufC, 2);
  CVTW(bufB, 1);  ISSUE(bufD, 3);
  // barrier 1: order LDS writes only; chunks c2,c3 remain in flight (no vmcnt drain)
  asm volatile("s_waitcnt lgkmcnt(0)" ::: "memory");
  __builtin_amdgcn_s_barrier();
  __builtin_amdgcn_sched_barrier(0);

  f32x4 acc[2][4] = {};

  // ---- step A: q = 0..3 (cols 0..127) ----
  #pragma unroll
  for (int q = 0; q < 4; ++q){
    half8 afr[2], bfr[4];
    #pragma unroll
    for (int nt = 0; nt < 4; ++nt)
      bfr[nt] = *reinterpret_cast<const half8*>(Bp + ((size_t)((q * 16 + w * 4 + nt) * 64 + lane)) * 8);
    #pragma unroll
    for (int mt = 0; mt < 2; ++mt){
      int row = mt * 16 + lr;
      int byte = (row * 512 + q * 64 + kg * 16) ^ ((row & 7) << 4);
      afr[mt] = *reinterpret_cast<const half8*>(Ab + byte);
    }
    #pragma unroll
    for (int mt = 0; mt < 2; ++mt)
      #pragma unroll
      for (int nt = 0; nt < 4; ++nt)
        acc[mt][nt] = __builtin_amdgcn_mfma_f32_16x16x32_f16(afr[mt], bfr[nt], acc[mt][nt], 0, 0, 0);
  }

  // write step-B columns (vmcnt wait on c2/c3 happens here; disjoint LDS columns)
  CVTW(bufC, 2); CVTW(bufD, 3);
  __syncthreads();

  // ---- step B: q = 4..7 (cols 128..255) ----
  #pragma unroll
  for (int q = 4; q < 8; ++q){
    half8 afr[2], bfr[4];
    #pragma unroll
    for (int nt = 0; nt < 4; ++nt)
      bfr[nt] = *reinterpret_cast<const half8*>(Bp + ((size_t)((q * 16 + w * 4 + nt) * 64 + lane)) * 8);
    #pragma unroll
    for (int mt = 0; mt < 2; ++mt){
      int row = mt * 16 + lr;
      int byte = (row * 512 + q * 64 + kg * 16) ^ ((row & 7) << 4);
      afr[mt] = *reinterpret_cast<const half8*>(Ab + byte);
    }
    #pragma unroll
    for (int mt = 0; mt < 2; ++mt)
      #pragma unroll
      for (int nt = 0; nt < 4; ++nt)
        acc[mt][nt] = __builtin_amdgcn_mfma_f32_16x16x32_f16(afr[mt], bfr[nt], acc[mt][nt], 0, 0, 0);
  }
#undef ISSUE
#undef CVTW

  // ---- a_t epilogue: BN + tanh + dot(x_h); reduce 16 cols (lr) per wave ----
  #pragma unroll
  for (int mt = 0; mt < 2; ++mt){
    #pragma unroll
    for (int r = 0; r < 4; ++r){
      int row = mt * 16 + kg * 4 + r;   // C/D: col=lane&15, row=(lane>>4)*4+reg
      float sc = bnsc[row], sh = bnsh[row];
      float sum = 0.f;
      #pragma unroll
      for (int nt = 0; nt < 4; ++nt){
        float hv = fmaf(acc[mt][nt][r], sc, sh);
        sum = fmaf(tanh_fast(hv), xhv[nt], sum);
      }
      sum += __shfl_xor(sum, 1);
      sum += __shfl_xor(sum, 2);
      sum += __shfl_xor(sum, 4);
      sum += __shfl_xor(sum, 8);
      if (lr == 0) red[w][row] = sum;
    }
  }
  __syncthreads();

  // ---- local softmax stats over 32 rows (wave 0, lanes 0..31) ----
  if (w == 0){
    float v = (lane < 32) ? (red[0][lane] + red[1][lane] + red[2][lane] + red[3][lane]) : -3.0e38f;
    float m_c = v;
    #pragma unroll
    for (int o = 1; o < 32; o <<= 1) m_c = fmaxf(m_c, __shfl_xor(m_c, o));
    float wv = __expf(v - m_c);          // lanes >=32: exp(-inf)=0
    if (lane < 32) wrow[lane] = wv;
    float z_c = wv;
    #pragma unroll
    for (int o = 1; o < 32; o <<= 1) z_c += __shfl_xor(z_c, o);
    if (lane == 0) mz[bid] = make_float2(m_c, z_c);
  }
  __syncthreads();

  // ---- weighted tile sum: P_c[d] = sum_rows wrow[row]*x[row][d], from LDS fp16 ----
  f32x4 pacc = {0.f, 0.f, 0.f, 0.f};
  #pragma unroll
  for (int r = 0; r < 8; ++r){
    int row = w * 8 + r;
    float wgt = wrow[row];
    int byte = (row * 512 + lane * 8) ^ ((row & 7) << 4);
    union { _Float16 h[4]; uint2 u; } pk;
    pk.u = *reinterpret_cast<const uint2*>(Ab + byte);
    pacc[0] = fmaf(wgt, (float)pk.h[0], pacc[0]);
    pacc[1] = fmaf(wgt, (float)pk.h[1], pacc[1]);
    pacc[2] = fmaf(wgt, (float)pk.h[2], pacc[2]);
    pacc[3] = fmaf(wgt, (float)pk.h[3], pacc[3]);
  }
  red4[w][lane] = pacc;
  __syncthreads();
  if (tid < 64){
    f32x4 r = red4[0][tid] + red4[1][tid] + red4[2][tid] + red4[3][tid];
    *reinterpret_cast<f32x4*>(Pbuf + (size_t)bid * 256 + tid * 4) = r;
  }
}

// ---------------- combine 128 chunks per b: flash-style merge + W2 scale ----------------
__global__ __launch_bounds__(256) void k_combine(const float* __restrict__ Pbuf,
    const float2* __restrict__ mz, const float* __restrict__ W2, float* __restrict__ out){
  int b = blockIdx.x, d = threadIdx.x;
  __shared__ float2 smz[128];
  if (d < 128) smz[d] = mz[b * 128 + d];
  __syncthreads();
  float M = smz[0].x;
  #pragma unroll 8
  for (int c = 1; c < 128; ++c) M = fmaxf(M, smz[c].x);
  float Z = 0.f, acc = 0.f;
  #pragma unroll 8
  for (int c = 0; c < 128; ++c){
    float e = __expf(smz[c].x - M);
    Z += smz[c].y * e;
    acc = fmaf(e, Pbuf[(size_t)(b * 128 + c) * 256 + d], acc);
  }
  out[b * 256 + d] = acc * W2[d] / Z;
}

extern "C" void kernel_launch(void* const* d_in, const int* in_sizes, int n_in,
                              void* d_out, int out_size, void* d_ws, size_t ws_size,
                              hipStream_t stream){
  const float* x_h    = (const float*)d_in[0];
  const float* x_hpre = (const float*)d_in[1];
  const float* W1     = (const float*)d_in[2];
  const float* W2     = (const float*)d_in[3];
  const float* gamma  = (const float*)d_in[4];
  const float* beta   = (const float*)d_in[5];
  const float* rmean  = (const float*)d_in[6];
  const float* rvar   = (const float*)d_in[7];
  float* out = (float*)d_out;

  char* ws = (char*)d_ws;
  _Float16* Bp = (_Float16*)(ws);            // 131072 B (fragment-ordered W1)
  float* bns   = (float*)(ws + 131072);      // 16 KB
  float* bnb   = (float*)(ws + 147456);      // 16 KB
  float* Pbuf  = (float*)(ws + 163840);      // 8 MB (64*128 chunks * 256 f32)
  float2* mzb  = (float2*)(ws + 8552448);    // 64 KB  (total ~8.6 MB)

  hipLaunchKernelGGL(k_prep,    dim3(256),  dim3(256), 0, stream, W1, gamma, beta, rmean, rvar, Bp, bns, bnb);
  hipLaunchKernelGGL(k_fused,   dim3(8192), dim3(256), 0, stream, x_h, x_hpre, Bp, bns, bnb, Pbuf, mzb);
  hipLaunchKernelGGL(k_combine, dim3(64),   dim3(256), 0, stream, Pbuf, mzb, W2, out);
}